// Round 4
// baseline (468.068 us; speedup 1.0000x reference)
//
#include <hip/hip_runtime.h>

// ChunkedLocalAttention on MI355X — round 4
// Changes vs round 3 (GEMMs only):
//  * k_gemm rewritten: 256x256 tile, 8 waves (2x4), BK=32, 4-slot circular LDS
//    (128 KiB), prefetch distance 3 with counted s_waitcnt vmcnt(8) (never 0
//    in steady state), raw s_barrier (no compiler vmcnt(0) drain), setprio
//    around MFMA clusters. BK=32 row stride (64B) spreads fragment ds_read_b128
//    across all banks -> no swizzle needed.
//  * M=32896 not /256: last M-tile clamps source rows; epilogue skips gm>=32896.
// cvt / transpose / attention stages unchanged from round 3.

typedef unsigned short u16;
typedef __attribute__((ext_vector_type(8))) short short8;
typedef __attribute__((ext_vector_type(8))) unsigned short u16x8;
typedef __attribute__((ext_vector_type(4))) float f32x4;

__device__ __forceinline__ u16 f2bf(float f) {
    unsigned u = __float_as_uint(f);
    u += 0x7fffu + ((u >> 16) & 1u);   // RTNE
    return (u16)(u >> 16);
}

#define MFMA_BF16(A, B, C) __builtin_amdgcn_mfma_f32_16x16x32_bf16((A), (B), (C), 0, 0, 0)

__device__ __forceinline__ void gload16(const u16* g, const short* l) {
    __builtin_amdgcn_global_load_lds(
        (__attribute__((address_space(1))) void*)g,
        (__attribute__((address_space(3))) void*)l, 16, 0, 0);
}

// ------------------------------------------------------------- x cvt + landmarks
__global__ __launch_bounds__(256) void k_cvtx(const float* __restrict__ x,
                                              u16* __restrict__ xa,
                                              float* __restrict__ part) {
    const int g = blockIdx.x;            // 0..511
    const int t = threadIdx.x;
    const float* base = x + (size_t)g * 64 * 768;
    u16* ob = xa + (size_t)g * 64 * 768;
    float s0 = 0.f, s1 = 0.f, s2 = 0.f;
    for (int r = 0; r < 64; ++r) {
        const size_t off = (size_t)r * 768;
        const float v0 = base[off + t], v1 = base[off + t + 256], v2 = base[off + t + 512];
        s0 += v0; s1 += v1; s2 += v2;
        ob[off + t] = f2bf(v0); ob[off + t + 256] = f2bf(v1); ob[off + t + 512] = f2bf(v2);
    }
    float* p = part + (size_t)g * 768;
    p[t] = s0; p[t + 256] = s1; p[t + 512] = s2;
}

__global__ void k_lmred(const float* __restrict__ part, u16* __restrict__ xa_lm) {
    const int bl = blockIdx.x;
    const int t = threadIdx.x;
    const float* p = part + (size_t)bl * 4 * 768;
    const float inv = 1.f / 256.f;
    for (int c = t; c < 768; c += 256) {
        const float s = p[c] + p[768 + c] + p[1536 + c] + p[2304 + c];
        xa_lm[(size_t)bl * 768 + c] = f2bf(s * inv);
    }
}

__global__ void k_cvtw(const float* __restrict__ qw, const float* __restrict__ kw,
                       const float* __restrict__ vw, const float* __restrict__ ow,
                       const float* __restrict__ qb, const float* __restrict__ kb,
                       const float* __restrict__ vb,
                       u16* __restrict__ wcat, u16* __restrict__ owb,
                       float* __restrict__ bcat) {
    const int yy = blockIdx.y;
    const int i = blockIdx.x * 256 + threadIdx.x;
    if (yy == 4) {
        if (i < 768)       bcat[i] = qb[i];
        else if (i < 1536) bcat[i] = kb[i - 768];
        else if (i < 2304) bcat[i] = vb[i - 1536];
        return;
    }
    const float* src = (yy == 0) ? qw : (yy == 1) ? kw : (yy == 2) ? vw : ow;
    u16* dst = (yy == 3) ? owb : wcat + (size_t)yy * 589824;
    const float4 v = ((const float4*)src)[i];
    ushort4 o;
    o.x = f2bf(v.x); o.y = f2bf(v.y); o.z = f2bf(v.z); o.w = f2bf(v.w);
    ((ushort4*)dst)[i] = o;
}

// ---------------------------------------------------------------- GEMM (256^2, pipelined)
// C = A(M x 768) * Bw(N x 768)^T + bias. 8 waves (2M x 4N), per-wave 128x64.
// BK=32, 4 LDS slots, prefetch distance 3, counted vmcnt, raw barriers.
template <int MODE>
__global__ __launch_bounds__(512, 2) void k_gemm(
    const u16* __restrict__ A, const u16* __restrict__ Bw, const float* __restrict__ bias,
    u16* __restrict__ q, u16* __restrict__ ktok, u16* __restrict__ vtok,
    u16* __restrict__ klm, u16* __restrict__ vlm, float* __restrict__ outf)
{
    __shared__ short lA[4 * 8192];       // [slot][256 rows][32 cols]
    __shared__ short lB[4 * 8192];
    const int t = threadIdx.x;           // 0..511
    const int wid = t >> 6, lane = t & 63, lr = lane & 15, lg = lane >> 4;
    const int wm = wid >> 2, wn = wid & 3;

    // bijective XCD swizzle (m204)
    const int gx = gridDim.x;
    const int nwg = gx * gridDim.y;
    const int orig = blockIdx.x + gx * blockIdx.y;
    const int qq = nwg >> 3, rr = nwg & 7, xcd = orig & 7, ii = orig >> 3;
    const int wg = (xcd < rr ? xcd * (qq + 1) : rr * (qq + 1) + (xcd - rr) * qq) + ii;
    const int m0 = (wg / gx) * 256, n0 = (wg % gx) * 256;

    // staging: thread covers 16B LDS unit idx = j*512+t -> row idx>>2, colgrp idx&3
    const int MMAX = (MODE == 0) ? 32895 : 32767;   // clamp A rows (pad tile)
    const int i0 = t, i1 = 512 + t;
    int ra0 = m0 + (i0 >> 2); if (ra0 > MMAX) ra0 = MMAX;
    int ra1 = m0 + (i1 >> 2); if (ra1 > MMAX) ra1 = MMAX;
    const u16* gA0 = A  + (size_t)ra0 * 768 + (i0 & 3) * 8;
    const u16* gA1 = A  + (size_t)ra1 * 768 + (i1 & 3) * 8;
    const u16* gB0 = Bw + (size_t)(n0 + (i0 >> 2)) * 768 + (i0 & 3) * 8;
    const u16* gB1 = Bw + (size_t)(n0 + (i1 >> 2)) * 768 + (i1 & 3) * 8;
    const int sd0 = wid * 512;           // wave-uniform LDS short offsets
    const int sd1 = 4096 + wid * 512;

#define STAGE(TT) { const int sb_ = ((TT) & 3) * 8192; const int ks_ = (TT) * 32;      \
    gload16(gA0 + ks_, &lA[sb_ + sd0]); gload16(gA1 + ks_, &lA[sb_ + sd1]);            \
    gload16(gB0 + ks_, &lB[sb_ + sd0]); gload16(gB1 + ks_, &lB[sb_ + sd1]); }

    f32x4 acc[8][4] = {};
    STAGE(0); STAGE(1); STAGE(2);        // 12 loads in flight

    for (int tt = 0; tt < 24; ++tt) {
        if (tt < 22)       asm volatile("s_waitcnt vmcnt(8)" ::: "memory");
        else if (tt == 22) asm volatile("s_waitcnt vmcnt(4)" ::: "memory");
        else               asm volatile("s_waitcnt vmcnt(0)" ::: "memory");
        __builtin_amdgcn_s_barrier();
        __builtin_amdgcn_sched_barrier(0);
        if (tt + 3 < 24) STAGE(tt + 3);  // lands in slot (tt-1)&3: readers done

        const short* sa = &lA[(tt & 3) * 8192];
        const short* sb = &lB[(tt & 3) * 8192];
        short8 bfr[4], afr[4];
#pragma unroll
        for (int nf = 0; nf < 4; ++nf)
            bfr[nf] = *(const short8*)&sb[(wn * 64 + nf * 16 + lr) * 32 + lg * 8];
#pragma unroll
        for (int mf = 0; mf < 4; ++mf)
            afr[mf] = *(const short8*)&sa[(wm * 128 + mf * 16 + lr) * 32 + lg * 8];
        __builtin_amdgcn_s_setprio(1);
#pragma unroll
        for (int mf = 0; mf < 4; ++mf)
#pragma unroll
            for (int nf = 0; nf < 4; ++nf)
                acc[mf][nf] = MFMA_BF16(afr[mf], bfr[nf], acc[mf][nf]);
        __builtin_amdgcn_s_setprio(0);
#pragma unroll
        for (int mf = 0; mf < 4; ++mf)
            afr[mf] = *(const short8*)&sa[(wm * 128 + (mf + 4) * 16 + lr) * 32 + lg * 8];
        __builtin_amdgcn_s_setprio(1);
#pragma unroll
        for (int mf = 0; mf < 4; ++mf)
#pragma unroll
            for (int nf = 0; nf < 4; ++nf)
                acc[mf + 4][nf] = MFMA_BF16(afr[mf], bfr[nf], acc[mf + 4][nf]);
        __builtin_amdgcn_s_setprio(0);
    }
#undef STAGE

    if (MODE == 0) {
        const int region = n0 / 768;         // 0=Q 1=K 2=V (uniform per block)
        u16* dst  = (region == 0) ? q : (region == 1) ? ktok : vtok;
        u16* dstl = (region == 1) ? klm : vlm;
#pragma unroll
        for (int nf = 0; nf < 4; ++nf) {
            const int gn = n0 + wn * 64 + nf * 16 + lr;
            const int nn = gn - region * 768;
            const int h = nn >> 6, d = nn & 63;
            const float bv = bias[gn];
#pragma unroll
            for (int mf = 0; mf < 8; ++mf) {
                const int gmb = m0 + wm * 128 + mf * 16 + lg * 4;
#pragma unroll
                for (int r = 0; r < 4; ++r) {
                    const int gm = gmb + r;
                    const u16 val = f2bf(acc[mf][nf][r] + bv);
                    if (gm < 32768) {
                        const int b = gm >> 13, s = gm & 8191;
                        dst[((size_t)(b * 12 + h) * 8192 + s) * 64 + d] = val;
                    } else if (gm < 32896 && region > 0) {
                        const int ii2 = gm - 32768;
                        dstl[((size_t)((ii2 >> 5) * 12 + h) * 32 + (ii2 & 31)) * 64 + d] = val;
                    }
                }
            }
        }
    } else {
#pragma unroll
        for (int nf = 0; nf < 4; ++nf) {
            const int gn = n0 + wn * 64 + nf * 16 + lr;
            const float bv = bias[gn];
#pragma unroll
            for (int mf = 0; mf < 8; ++mf) {
                const int gmb = m0 + wm * 128 + mf * 16 + lg * 4;
#pragma unroll
                for (int r = 0; r < 4; ++r)
                    outf[(size_t)(gmb + r) * 768 + gn] = acc[mf][nf][r] + bv;
            }
        }
    }
}

// ---------------------------------------------------------------- V transpose
__global__ __launch_bounds__(256) void k_tv(const u16* __restrict__ vtok, u16* __restrict__ vt) {
    __shared__ u16 tl[64 * 72];
    const int t = threadIdx.x;
    const int bh = blockIdx.x >> 7;
    const int s0 = (blockIdx.x & 127) * 64;
#pragma unroll
    for (int i = 0; i < 2; ++i) {
        const int qq = t + 256 * i;
        const int s = qq >> 3, c = qq & 7;
        *(uint4*)&tl[s * 72 + c * 8] =
            *(const uint4*)(vtok + ((size_t)bh * 8192 + s0 + s) * 64 + c * 8);
    }
    __syncthreads();
    const int d = t >> 2, sc = t & 3;
    u16x8 a, b2;
#pragma unroll
    for (int j = 0; j < 8; ++j) a[j] = tl[(sc * 16 + j) * 72 + d];
#pragma unroll
    for (int j = 0; j < 8; ++j) b2[j] = tl[(sc * 16 + 8 + j) * 72 + d];
    u16* o = vt + ((size_t)bh * 64 + d) * 8192 + s0 + sc * 16;
    *(u16x8*)(o) = a;
    *(u16x8*)(o + 8) = b2;
}

__global__ void k_tvlm(const u16* __restrict__ vlm, u16* __restrict__ vlmt) {
    const int e = blockIdx.x * 256 + threadIdx.x;
    if (e >= 98304) return;
    const int bh = e >> 11, rem = e & 2047, d = rem >> 5, lm = rem & 31;
    vlmt[(size_t)bh * 2048 + d * 32 + lm] = vlm[(size_t)bh * 2048 + lm * 64 + d];
}

// ---------------------------------------------------------------- attention
__global__ __launch_bounds__(256) void k_attn(
    const u16* __restrict__ q, const u16* __restrict__ ktok,
    const u16* __restrict__ klm, const u16* __restrict__ vt,
    const u16* __restrict__ vlmt, u16* __restrict__ ao)
{
    __shared__ short kls[2][32 * 72];
    __shared__ short vls[2][64 * 40];
    __shared__ short pls[4][64 * 40];
    const int t = threadIdx.x, wid = t >> 6, l = t & 63, lr = l & 15, lg = l >> 4;
    const int idx = blockIdx.x;
    const int qt = idx & 1;
    const int h  = (idx >> 1) % 12;
    const int cb = (idx >> 1) / 12;
    const int c  = cb & 15, b = cb >> 4;
    const int bh = b * 12 + h;
    const int sb = c * 512 + qt * 256 + wid * 64;

    short8 qf[4][2];
#pragma unroll
    for (int mf = 0; mf < 4; ++mf)
#pragma unroll
        for (int kf = 0; kf < 2; ++kf)
            qf[mf][kf] = *(const short8*)(q + ((size_t)bh * 8192 + sb + mf * 16 + lr) * 64
                                            + kf * 32 + lg * 8);

    f32x4 O[4][4] = {};
    float lsum[4][4] = {};

    short* pw = &pls[wid][0];
    const int kn = t >> 3, kko = (t & 7) * 8;
    const int kctx = (kn < 16) ? (kn * 2) : ((kn - 16) * 2 + 1);
    const int vd = t >> 2, vco = (t & 3) * 8;

    auto kaddr = [&](int ti) -> const u16* {
        if (ti == 0) return klm + ((size_t)bh * 32 + kctx) * 64 + kko;
        return ktok + ((size_t)bh * 8192 + c * 512 + (ti - 1) * 32 + kctx) * 64 + kko;
    };
    auto vaddr = [&](int ti) -> const u16* {
        if (ti == 0) return vlmt + ((size_t)bh * 64 + vd) * 32 + vco;
        return vt + ((size_t)bh * 64 + vd) * 8192 + c * 512 + (ti - 1) * 32 + vco;
    };

    {
        const uint4 rk0 = *(const uint4*)kaddr(0);
        const uint4 rv0 = *(const uint4*)vaddr(0);
        *(uint4*)&kls[0][kn * 72 + kko] = rk0;
        *(uint4*)&vls[0][vd * 40 + vco] = rv0;
    }
    __syncthreads();

    for (int ti = 0; ti < 17; ++ti) {
        const int cur = ti & 1, nxt = cur ^ 1;
        uint4 rk, rv;
        if (ti < 16) { rk = *(const uint4*)kaddr(ti + 1); rv = *(const uint4*)vaddr(ti + 1); }

        f32x4 sc[4][2] = {};
#pragma unroll
        for (int kf = 0; kf < 2; ++kf) {
            const short8 b0 = *(const short8*)&kls[cur][(lr)      * 72 + kf * 32 + lg * 8];
            const short8 b1 = *(const short8*)&kls[cur][(16 + lr) * 72 + kf * 32 + lg * 8];
#pragma unroll
            for (int mf = 0; mf < 4; ++mf) {
                sc[mf][0] = MFMA_BF16(qf[mf][kf], b0, sc[mf][0]);
                sc[mf][1] = MFMA_BF16(qf[mf][kf], b1, sc[mf][1]);
            }
        }

#pragma unroll
        for (int mf = 0; mf < 4; ++mf) {
#pragma unroll
            for (int r = 0; r < 4; ++r) {
                const float p0 = __expf(sc[mf][0][r] * 0.125f);
                const float p1 = __expf(sc[mf][1][r] * 0.125f);
                lsum[mf][r] += p0 + p1;
                unsigned pk;
                asm("v_cvt_pk_bf16_f32 %0, %1, %2" : "=v"(pk) : "v"(p0), "v"(p1));
                const int prow = mf * 16 + lg * 4 + r;
                ((unsigned*)pw)[prow * 20 + lr] = pk;
            }
        }

        short8 vb[4];
#pragma unroll
        for (int df = 0; df < 4; ++df)
            vb[df] = *(const short8*)&vls[cur][(df * 16 + lr) * 40 + lg * 8];
#pragma unroll
        for (int mf = 0; mf < 4; ++mf) {
            const short8 pa = *(const short8*)&pw[(mf * 16 + lr) * 40 + lg * 8];
#pragma unroll
            for (int df = 0; df < 4; ++df)
                O[mf][df] = MFMA_BF16(pa, vb[df], O[mf][df]);
        }

        if (ti < 16) {
            *(uint4*)&kls[nxt][kn * 72 + kko] = rk;
            *(uint4*)&vls[nxt][vd * 40 + vco] = rv;
        }
        __syncthreads();
    }

#pragma unroll
    for (int mf = 0; mf < 4; ++mf)
#pragma unroll
        for (int r = 0; r < 4; ++r) {
            float lv = lsum[mf][r];
            lv += __shfl_xor(lv, 1); lv += __shfl_xor(lv, 2);
            lv += __shfl_xor(lv, 4); lv += __shfl_xor(lv, 8);
            const float inv = 1.f / lv;
            const int srow = sb + mf * 16 + lg * 4 + r;
#pragma unroll
            for (int df = 0; df < 4; ++df)
                ao[((size_t)b * 8192 + srow) * 768 + h * 64 + df * 16 + lr] =
                    f2bf(O[mf][df][r] * inv);
        }
}

// ---------------------------------------------------------------- launch
extern "C" void kernel_launch(void* const* d_in, const int* in_sizes, int n_in,
                              void* d_out, int out_size, void* d_ws, size_t ws_size,
                              hipStream_t stream)
{
    const float* x  = (const float*)d_in[0];
    const float* qw = (const float*)d_in[1];
    const float* qb = (const float*)d_in[2];
    const float* kw = (const float*)d_in[3];
    const float* kb = (const float*)d_in[4];
    const float* vw = (const float*)d_in[5];
    const float* vb = (const float*)d_in[6];
    const float* ow = (const float*)d_in[7];
    const float* ob = (const float*)d_in[8];
    float* out = (float*)d_out;

    u16* xa     = (u16*)d_ws;                        // 32896 x 768
    u16* wcat   = xa + (size_t)32896 * 768;          // 2304 x 768
    u16* owb    = wcat + (size_t)2304 * 768;         // 768 x 768
    float* bcat = (float*)(owb + (size_t)768 * 768); // 2304
    u16* qx     = (u16*)(bcat + 2304);               // [b,h,s,d]
    u16* ktok   = qx   + (size_t)32768 * 768;
    u16* vtok   = ktok + (size_t)32768 * 768;
    u16* vt     = vtok + (size_t)32768 * 768;        // [b,h,d,s]
    u16* klm    = vt + (size_t)32768 * 768;          // [b,h,l,d]
    u16* vlm    = klm + 98304;
    u16* vlmt   = vlm + 98304;                       // [b,h,d,l]
    float* part = (float*)(vlmt + 98304);            // 512 x 768
    u16* ao     = xa;                                // alias

    k_cvtx<<<512, 256, 0, stream>>>(x, xa, part);
    k_lmred<<<128, 256, 0, stream>>>(part, xa + (size_t)32768 * 768);
    k_cvtw<<<dim3(576, 5), 256, 0, stream>>>(qw, kw, vw, ow, qb, kb, vb, wcat, owb, bcat);

    k_gemm<0><<<dim3(9, 129), 512, 0, stream>>>(xa, wcat, bcat,
                                                qx, ktok, vtok, klm, vlm, nullptr);
    k_tv<<<6144, 256, 0, stream>>>(vtok, vt);
    k_tvlm<<<384, 256, 0, stream>>>(vlm, vlmt);
    k_attn<<<1536, 256, 0, stream>>>(qx, ktok, klm, vt, vlmt, ao);
    k_gemm<1><<<dim3(3, 128), 512, 0, stream>>>(ao, owb, ob,
                                                nullptr, nullptr, nullptr, nullptr, nullptr, out);
}

// Round 5
// 402.823 us; speedup vs baseline: 1.1620x; 1.1620x over previous
//
#include <hip/hip_runtime.h>

// ChunkedLocalAttention on MI355X — round 5
// Changes vs round 4 (GEMMs only): m201-style 8-phase 256x256 schedule.
//  * BK=64, 2 K-tile LDS double buffer (128 KiB), 8 waves (2x4).
//  * XOR swizzle on 16B units (c ^= row&7): pre-swizzled GLOBAL source +
//    swizzled ds_read, linear global_load_lds dest (both-sides rule).
//  * 4 phases/K-tile, 16 MFMA each, setprio(1) clusters, counted vmcnt(6)
//    (vmcnt(0) only at the final K-tile). Stage lead 4-5 phases.
//  * Race-free by construction: B-halves staged into a slot read a full span
//    earlier; A-halves staged only after the q4 barrier (A last read in q3).
// cvt / transpose / attention unchanged from round 4.

typedef unsigned short u16;
typedef __attribute__((ext_vector_type(8))) short short8;
typedef __attribute__((ext_vector_type(8))) unsigned short u16x8;
typedef __attribute__((ext_vector_type(4))) float f32x4;

__device__ __forceinline__ u16 f2bf(float f) {
    unsigned u = __float_as_uint(f);
    u += 0x7fffu + ((u >> 16) & 1u);   // RTNE
    return (u16)(u >> 16);
}

#define MFMA_BF16(A, B, C) __builtin_amdgcn_mfma_f32_16x16x32_bf16((A), (B), (C), 0, 0, 0)

__device__ __forceinline__ void gload16(const u16* g, const short* l) {
    __builtin_amdgcn_global_load_lds(
        (__attribute__((address_space(1))) void*)g,
        (__attribute__((address_space(3))) void*)l, 16, 0, 0);
}

// ------------------------------------------------------------- x cvt + landmarks
__global__ __launch_bounds__(256) void k_cvtx(const float* __restrict__ x,
                                              u16* __restrict__ xa,
                                              float* __restrict__ part) {
    const int g = blockIdx.x;            // 0..511
    const int t = threadIdx.x;
    const float* base = x + (size_t)g * 64 * 768;
    u16* ob = xa + (size_t)g * 64 * 768;
    float s0 = 0.f, s1 = 0.f, s2 = 0.f;
    for (int r = 0; r < 64; ++r) {
        const size_t off = (size_t)r * 768;
        const float v0 = base[off + t], v1 = base[off + t + 256], v2 = base[off + t + 512];
        s0 += v0; s1 += v1; s2 += v2;
        ob[off + t] = f2bf(v0); ob[off + t + 256] = f2bf(v1); ob[off + t + 512] = f2bf(v2);
    }
    float* p = part + (size_t)g * 768;
    p[t] = s0; p[t + 256] = s1; p[t + 512] = s2;
}

__global__ void k_lmred(const float* __restrict__ part, u16* __restrict__ xa_lm) {
    const int bl = blockIdx.x;
    const int t = threadIdx.x;
    const float* p = part + (size_t)bl * 4 * 768;
    const float inv = 1.f / 256.f;
    for (int c = t; c < 768; c += 256) {
        const float s = p[c] + p[768 + c] + p[1536 + c] + p[2304 + c];
        xa_lm[(size_t)bl * 768 + c] = f2bf(s * inv);
    }
}

__global__ void k_cvtw(const float* __restrict__ qw, const float* __restrict__ kw,
                       const float* __restrict__ vw, const float* __restrict__ ow,
                       const float* __restrict__ qb, const float* __restrict__ kb,
                       const float* __restrict__ vb,
                       u16* __restrict__ wcat, u16* __restrict__ owb,
                       float* __restrict__ bcat) {
    const int yy = blockIdx.y;
    const int i = blockIdx.x * 256 + threadIdx.x;
    if (yy == 4) {
        if (i < 768)       bcat[i] = qb[i];
        else if (i < 1536) bcat[i] = kb[i - 768];
        else if (i < 2304) bcat[i] = vb[i - 1536];
        return;
    }
    const float* src = (yy == 0) ? qw : (yy == 1) ? kw : (yy == 2) ? vw : ow;
    u16* dst = (yy == 3) ? owb : wcat + (size_t)yy * 589824;
    const float4 v = ((const float4*)src)[i];
    ushort4 o;
    o.x = f2bf(v.x); o.y = f2bf(v.y); o.z = f2bf(v.z); o.w = f2bf(v.w);
    ((ushort4*)dst)[i] = o;
}

// ------------------------------------------------ GEMM: 256x256, 8-phase, BK=64
// C = A(M x 768) * Bw(N x 768)^T + bias. LDS unit u (16B) of a [256][64s] tile
// holds global (row=u>>3, cu=(u&7)^(row&7)) -> fragment ds_reads conflict-free.
template <int MODE>
__global__ __launch_bounds__(512, 1) void k_gemm(
    const u16* __restrict__ A, const u16* __restrict__ Bw, const float* __restrict__ bias,
    u16* __restrict__ q, u16* __restrict__ ktok, u16* __restrict__ vtok,
    u16* __restrict__ klm, u16* __restrict__ vlm, float* __restrict__ outf)
{
    __shared__ short lA[2 * 16384];      // [slot][256r][8 units][8 shorts]
    __shared__ short lB[2 * 16384];
    const int t = threadIdx.x;           // 0..511
    const int wid = t >> 6, lane = t & 63, lr = lane & 15, lg = lane >> 4;
    const int wm = wid >> 2, wn = wid & 3;

    // bijective XCD swizzle (m204)
    const int gx = gridDim.x;
    const int nwg = gx * gridDim.y;
    const int orig = blockIdx.x + gx * blockIdx.y;
    const int qq = nwg >> 3, rr = nwg & 7, xcd = orig & 7, ii = orig >> 3;
    const int wg = (xcd < rr ? xcd * (qq + 1) : rr * (qq + 1) + (xcd - rr) * qq) + ii;
    const int m0 = (wg / gx) * 256, n0 = (wg % gx) * 256;

    // staging source precompute (pre-swizzled global col): pass j covers unit
    // u = j*512 + t of a 128-row half-tile; row=u>>3, col unit = (u&7)^(row&7).
    const int MMAX = (MODE == 0) ? 32895 : 32767;
    const int u0 = t, u1 = 512 + t;
    const int r0 = u0 >> 3, c0 = ((u0 & 7) ^ (r0 & 7)) * 8;
    const int r1 = u1 >> 3, c1 = ((u1 & 7) ^ (r1 & 7)) * 8;
    const u16* pA[2][2]; const u16* pB[2][2];
#pragma unroll
    for (int h = 0; h < 2; ++h) {
        int ra0 = m0 + h * 128 + r0; if (ra0 > MMAX) ra0 = MMAX;
        int ra1 = m0 + h * 128 + r1; if (ra1 > MMAX) ra1 = MMAX;
        pA[h][0] = A + (size_t)ra0 * 768 + c0;
        pA[h][1] = A + (size_t)ra1 * 768 + c1;
        pB[h][0] = Bw + (size_t)(n0 + h * 128 + r0) * 768 + c0;
        pB[h][1] = Bw + (size_t)(n0 + h * 128 + r1) * 768 + c1;
    }
    // swizzled ds_read col offsets (shorts): row&7 == lr&7 for all frags
    const int sa0 = ((lg) ^ (lr & 7)) * 8;
    const int sa1 = ((4 + lg) ^ (lr & 7)) * 8;

#define STG_A(S, H, T) { gload16(pA[H][0] + (T) * 64, &lA[(S)*16384 + (H)*8192 + wid*512]);      \
                         gload16(pA[H][1] + (T) * 64, &lA[(S)*16384 + (H)*8192 + 4096 + wid*512]); }
#define STG_B(S, H, T) { gload16(pB[H][0] + (T) * 64, &lB[(S)*16384 + (H)*8192 + wid*512]);      \
                         gload16(pB[H][1] + (T) * 64, &lB[(S)*16384 + (H)*8192 + 4096 + wid*512]); }

    f32x4 acc[8][4] = {};
    short8 aq[4][2], bq[4][2];

    // prologue: tile0 fully + tile1 A-halves (12 loads in flight)
    STG_A(0, 0, 0); STG_A(0, 1, 0); STG_B(0, 0, 0); STG_B(0, 1, 0);
    STG_A(1, 0, 1); STG_A(1, 1, 1);

#pragma unroll
    for (int T = 0; T < 12; ++T) {
        const int s = T & 1;
        const short* sa = &lA[s * 16384];
        const short* sbm = &lB[s * 16384];
        // ---------- q1: stage B-h0(T+1); vmcnt; barrier; read a0-3,b0-3; MFMA mf0-3 x nf0-1
        if (T + 1 < 12) STG_B(s ^ 1, 0, T + 1);
        if (T < 11) asm volatile("s_waitcnt vmcnt(6)" ::: "memory");
        else        asm volatile("s_waitcnt vmcnt(0)" ::: "memory");
        __builtin_amdgcn_s_barrier();
        __builtin_amdgcn_sched_barrier(0);
#pragma unroll
        for (int mf = 0; mf < 4; ++mf) {
            const int rb = (wm * 128 + mf * 16 + lr) * 64;
            aq[mf][0] = *(const short8*)&sa[rb + sa0];
            aq[mf][1] = *(const short8*)&sa[rb + sa1];
        }
#pragma unroll
        for (int nf = 0; nf < 4; ++nf) {
            const int rb = (wn * 64 + nf * 16 + lr) * 64;
            bq[nf][0] = *(const short8*)&sbm[rb + sa0];
            bq[nf][1] = *(const short8*)&sbm[rb + sa1];
        }
        __builtin_amdgcn_s_setprio(1);
#pragma unroll
        for (int mf = 0; mf < 4; ++mf)
#pragma unroll
            for (int nf = 0; nf < 2; ++nf)
#pragma unroll
                for (int kf = 0; kf < 2; ++kf)
                    acc[mf][nf] = MFMA_BF16(aq[mf][kf], bq[nf][kf], acc[mf][nf]);
        __builtin_amdgcn_s_setprio(0);
        // ---------- q2: stage B-h1(T+1); MFMA mf0-3 x nf2-3
        if (T + 1 < 12) STG_B(s ^ 1, 1, T + 1);
        __builtin_amdgcn_s_barrier();
        __builtin_amdgcn_s_setprio(1);
#pragma unroll
        for (int mf = 0; mf < 4; ++mf)
#pragma unroll
            for (int nf = 2; nf < 4; ++nf)
#pragma unroll
                for (int kf = 0; kf < 2; ++kf)
                    acc[mf][nf] = MFMA_BF16(aq[mf][kf], bq[nf][kf], acc[mf][nf]);
        __builtin_amdgcn_s_setprio(0);
        // ---------- q3: read a4-7 (reuse regs); MFMA mf4-7 x nf0-1
        __builtin_amdgcn_s_barrier();
#pragma unroll
        for (int mf = 0; mf < 4; ++mf) {
            const int rb = (wm * 128 + (mf + 4) * 16 + lr) * 64;
            aq[mf][0] = *(const short8*)&sa[rb + sa0];
            aq[mf][1] = *(const short8*)&sa[rb + sa1];
        }
        __builtin_amdgcn_s_setprio(1);
#pragma unroll
        for (int mf = 0; mf < 4; ++mf)
#pragma unroll
            for (int nf = 0; nf < 2; ++nf)
#pragma unroll
                for (int kf = 0; kf < 2; ++kf)
                    acc[mf + 4][nf] = MFMA_BF16(aq[mf][kf], bq[nf][kf], acc[mf + 4][nf]);
        __builtin_amdgcn_s_setprio(0);
        // ---------- q4: barrier; stage A(T+2) (A last read in q3); MFMA mf4-7 x nf2-3
        __builtin_amdgcn_s_barrier();
        if (T + 2 < 12) { STG_A(s, 0, T + 2); STG_A(s, 1, T + 2); }
        __builtin_amdgcn_s_setprio(1);
#pragma unroll
        for (int mf = 0; mf < 4; ++mf)
#pragma unroll
            for (int nf = 2; nf < 4; ++nf)
#pragma unroll
                for (int kf = 0; kf < 2; ++kf)
                    acc[mf + 4][nf] = MFMA_BF16(aq[mf][kf], bq[nf][kf], acc[mf + 4][nf]);
        __builtin_amdgcn_s_setprio(0);
    }
#undef STG_A
#undef STG_B

    if (MODE == 0) {
        const int region = n0 / 768;         // 0=Q 1=K 2=V (uniform per block)
        u16* dst  = (region == 0) ? q : (region == 1) ? ktok : vtok;
        u16* dstl = (region == 1) ? klm : vlm;
#pragma unroll
        for (int nf = 0; nf < 4; ++nf) {
            const int gn = n0 + wn * 64 + nf * 16 + lr;
            const int nn = gn - region * 768;
            const int h = nn >> 6, d = nn & 63;
            const float bv = bias[gn];
#pragma unroll
            for (int mf = 0; mf < 8; ++mf) {
                const int gmb = m0 + wm * 128 + mf * 16 + lg * 4;
#pragma unroll
                for (int r = 0; r < 4; ++r) {
                    const int gm = gmb + r;
                    const u16 val = f2bf(acc[mf][nf][r] + bv);
                    if (gm < 32768) {
                        const int b = gm >> 13, sidx = gm & 8191;
                        dst[((size_t)(b * 12 + h) * 8192 + sidx) * 64 + d] = val;
                    } else if (gm < 32896 && region > 0) {
                        const int ii2 = gm - 32768;
                        dstl[((size_t)((ii2 >> 5) * 12 + h) * 32 + (ii2 & 31)) * 64 + d] = val;
                    }
                }
            }
        }
    } else {
#pragma unroll
        for (int nf = 0; nf < 4; ++nf) {
            const int gn = n0 + wn * 64 + nf * 16 + lr;
            const float bv = bias[gn];
#pragma unroll
            for (int mf = 0; mf < 8; ++mf) {
                const int gmb = m0 + wm * 128 + mf * 16 + lg * 4;
#pragma unroll
                for (int r = 0; r < 4; ++r)
                    outf[(size_t)(gmb + r) * 768 + gn] = acc[mf][nf][r] + bv;
            }
        }
    }
}

// ---------------------------------------------------------------- V transpose
__global__ __launch_bounds__(256) void k_tv(const u16* __restrict__ vtok, u16* __restrict__ vt) {
    __shared__ u16 tl[64 * 72];
    const int t = threadIdx.x;
    const int bh = blockIdx.x >> 7;
    const int s0 = (blockIdx.x & 127) * 64;
#pragma unroll
    for (int i = 0; i < 2; ++i) {
        const int qq = t + 256 * i;
        const int s = qq >> 3, c = qq & 7;
        *(uint4*)&tl[s * 72 + c * 8] =
            *(const uint4*)(vtok + ((size_t)bh * 8192 + s0 + s) * 64 + c * 8);
    }
    __syncthreads();
    const int d = t >> 2, sc = t & 3;
    u16x8 a, b2;
#pragma unroll
    for (int j = 0; j < 8; ++j) a[j] = tl[(sc * 16 + j) * 72 + d];
#pragma unroll
    for (int j = 0; j < 8; ++j) b2[j] = tl[(sc * 16 + 8 + j) * 72 + d];
    u16* o = vt + ((size_t)bh * 64 + d) * 8192 + s0 + sc * 16;
    *(u16x8*)(o) = a;
    *(u16x8*)(o + 8) = b2;
}

__global__ void k_tvlm(const u16* __restrict__ vlm, u16* __restrict__ vlmt) {
    const int e = blockIdx.x * 256 + threadIdx.x;
    if (e >= 98304) return;
    const int bh = e >> 11, rem = e & 2047, d = rem >> 5, lm = rem & 31;
    vlmt[(size_t)bh * 2048 + d * 32 + lm] = vlm[(size_t)bh * 2048 + lm * 64 + d];
}

// ---------------------------------------------------------------- attention
__global__ __launch_bounds__(256) void k_attn(
    const u16* __restrict__ q, const u16* __restrict__ ktok,
    const u16* __restrict__ klm, const u16* __restrict__ vt,
    const u16* __restrict__ vlmt, u16* __restrict__ ao)
{
    __shared__ short kls[2][32 * 72];
    __shared__ short vls[2][64 * 40];
    __shared__ short pls[4][64 * 40];
    const int t = threadIdx.x, wid = t >> 6, l = t & 63, lr = l & 15, lg = l >> 4;
    const int idx = blockIdx.x;
    const int qt = idx & 1;
    const int h  = (idx >> 1) % 12;
    const int cb = (idx >> 1) / 12;
    const int c  = cb & 15, b = cb >> 4;
    const int bh = b * 12 + h;
    const int sb = c * 512 + qt * 256 + wid * 64;

    short8 qf[4][2];
#pragma unroll
    for (int mf = 0; mf < 4; ++mf)
#pragma unroll
        for (int kf = 0; kf < 2; ++kf)
            qf[mf][kf] = *(const short8*)(q + ((size_t)bh * 8192 + sb + mf * 16 + lr) * 64
                                            + kf * 32 + lg * 8);

    f32x4 O[4][4] = {};
    float lsum[4][4] = {};

    short* pw = &pls[wid][0];
    const int kn = t >> 3, kko = (t & 7) * 8;
    const int kctx = (kn < 16) ? (kn * 2) : ((kn - 16) * 2 + 1);
    const int vd = t >> 2, vco = (t & 3) * 8;

    auto kaddr = [&](int ti) -> const u16* {
        if (ti == 0) return klm + ((size_t)bh * 32 + kctx) * 64 + kko;
        return ktok + ((size_t)bh * 8192 + c * 512 + (ti - 1) * 32 + kctx) * 64 + kko;
    };
    auto vaddr = [&](int ti) -> const u16* {
        if (ti == 0) return vlmt + ((size_t)bh * 64 + vd) * 32 + vco;
        return vt + ((size_t)bh * 64 + vd) * 8192 + c * 512 + (ti - 1) * 32 + vco;
    };

    {
        const uint4 rk0 = *(const uint4*)kaddr(0);
        const uint4 rv0 = *(const uint4*)vaddr(0);
        *(uint4*)&kls[0][kn * 72 + kko] = rk0;
        *(uint4*)&vls[0][vd * 40 + vco] = rv0;
    }
    __syncthreads();

    for (int ti = 0; ti < 17; ++ti) {
        const int cur = ti & 1, nxt = cur ^ 1;
        uint4 rk, rv;
        if (ti < 16) { rk = *(const uint4*)kaddr(ti + 1); rv = *(const uint4*)vaddr(ti + 1); }

        f32x4 sc[4][2] = {};
#pragma unroll
        for (int kf = 0; kf < 2; ++kf) {
            const short8 b0 = *(const short8*)&kls[cur][(lr)      * 72 + kf * 32 + lg * 8];
            const short8 b1 = *(const short8*)&kls[cur][(16 + lr) * 72 + kf * 32 + lg * 8];
#pragma unroll
            for (int mf = 0; mf < 4; ++mf) {
                sc[mf][0] = MFMA_BF16(qf[mf][kf], b0, sc[mf][0]);
                sc[mf][1] = MFMA_BF16(qf[mf][kf], b1, sc[mf][1]);
            }
        }

#pragma unroll
        for (int mf = 0; mf < 4; ++mf) {
#pragma unroll
            for (int r = 0; r < 4; ++r) {
                const float p0 = __expf(sc[mf][0][r] * 0.125f);
                const float p1 = __expf(sc[mf][1][r] * 0.125f);
                lsum[mf][r] += p0 + p1;
                unsigned pk;
                asm("v_cvt_pk_bf16_f32 %0, %1, %2" : "=v"(pk) : "v"(p0), "v"(p1));
                const int prow = mf * 16 + lg * 4 + r;
                ((unsigned*)pw)[prow * 20 + lr] = pk;
            }
        }

        short8 vb[4];
#pragma unroll
        for (int df = 0; df < 4; ++df)
            vb[df] = *(const short8*)&vls[cur][(df * 16 + lr) * 40 + lg * 8];
#pragma unroll
        for (int mf = 0; mf < 4; ++mf) {
            const short8 pa = *(const short8*)&pw[(mf * 16 + lr) * 40 + lg * 8];
#pragma unroll
            for (int df = 0; df < 4; ++df)
                O[mf][df] = MFMA_BF16(pa, vb[df], O[mf][df]);
        }

        if (ti < 16) {
            *(uint4*)&kls[nxt][kn * 72 + kko] = rk;
            *(uint4*)&vls[nxt][vd * 40 + vco] = rv;
        }
        __syncthreads();
    }

#pragma unroll
    for (int mf = 0; mf < 4; ++mf)
#pragma unroll
        for (int r = 0; r < 4; ++r) {
            float lv = lsum[mf][r];
            lv += __shfl_xor(lv, 1); lv += __shfl_xor(lv, 2);
            lv += __shfl_xor(lv, 4); lv += __shfl_xor(lv, 8);
            const float inv = 1.f / lv;
            const int srow = sb + mf * 16 + lg * 4 + r;
#pragma unroll
            for (int df = 0; df < 4; ++df)
                ao[((size_t)b * 8192 + srow) * 768 + h * 64 + df * 16 + lr] =
                    f2bf(O[mf][df][r] * inv);
        }
}

// ---------------------------------------------------------------- launch
extern "C" void kernel_launch(void* const* d_in, const int* in_sizes, int n_in,
                              void* d_out, int out_size, void* d_ws, size_t ws_size,
                              hipStream_t stream)
{
    const float* x  = (const float*)d_in[0];
    const float* qw = (const float*)d_in[1];
    const float* qb = (const float*)d_in[2];
    const float* kw = (const float*)d_in[3];
    const float* kb = (const float*)d_in[4];
    const float* vw = (const float*)d_in[5];
    const float* vb = (const float*)d_in[6];
    const float* ow = (const float*)d_in[7];
    const float* ob = (const float*)d_in[8];
    float* out = (float*)d_out;

    u16* xa     = (u16*)d_ws;                        // 32896 x 768
    u16* wcat   = xa + (size_t)32896 * 768;          // 2304 x 768
    u16* owb    = wcat + (size_t)2304 * 768;         // 768 x 768
    float* bcat = (float*)(owb + (size_t)768 * 768); // 2304
    u16* qx     = (u16*)(bcat + 2304);               // [b,h,s,d]
    u16* ktok   = qx   + (size_t)32768 * 768;
    u16* vtok   = ktok + (size_t)32768 * 768;
    u16* vt     = vtok + (size_t)32768 * 768;        // [b,h,d,s]
    u16* klm    = vt + (size_t)32768 * 768;          // [b,h,l,d]
    u16* vlm    = klm + 98304;
    u16* vlmt   = vlm + 98304;                       // [b,h,d,l]
    float* part = (float*)(vlmt + 98304);            // 512 x 768
    u16* ao     = xa;                                // alias

    k_cvtx<<<512, 256, 0, stream>>>(x, xa, part);
    k_lmred<<<128, 256, 0, stream>>>(part, xa + (size_t)32768 * 768);
    k_cvtw<<<dim3(576, 5), 256, 0, stream>>>(qw, kw, vw, ow, qb, kb, vb, wcat, owb, bcat);

    k_gemm<0><<<dim3(9, 129), 512, 0, stream>>>(xa, wcat, bcat,
                                                qx, ktok, vtok, klm, vlm, nullptr);
    k_tv<<<6144, 256, 0, stream>>>(vtok, vt);
    k_tvlm<<<384, 256, 0, stream>>>(vlm, vlmt);
    k_attn<<<1536, 256, 0, stream>>>(qx, ktok, klm, vt, vlmt, ao);
    k_gemm<1><<<dim3(3, 128), 512, 0, stream>>>(ao, owb, ob,
                                                nullptr, nullptr, nullptr, nullptr, nullptr, out);
}

// Round 8
// 351.524 us; speedup vs baseline: 1.3315x; 1.1459x over previous
//
#include <hip/hip_runtime.h>

// ChunkedLocalAttention on MI355X — round 8
// Rounds 6/7 failed (~3.7e-2) with the LDS-repack epilogues; mapping traces
// clean, so the repack surface is quarantined. This round = round 5 (passed,
// 403us) + ONE slice-free change:
//  * V region of k_gemm<0> epilogue: each lane's acc[mf][nf][0..3] are 4
//    consecutive rows at fixed col -> in transposed [d][s] layout that is a
//    contiguous ushort4 -> packed 8B stores DIRECT to vt/vlmt.
//    k_tv / k_tvlm deleted; vtok / vlm buffers removed.
//  * Everything else byte-identical to round 5 (K-loops, Q/K scalar stores,
//    attn kernel, cvtx/lmred/cvtw).

typedef unsigned short u16;
typedef __attribute__((ext_vector_type(8))) short short8;
typedef __attribute__((ext_vector_type(4))) float f32x4;

__device__ __forceinline__ u16 f2bf(float f) {
    unsigned u = __float_as_uint(f);
    u += 0x7fffu + ((u >> 16) & 1u);   // RTNE
    return (u16)(u >> 16);
}

#define MFMA_BF16(A, B, C) __builtin_amdgcn_mfma_f32_16x16x32_bf16((A), (B), (C), 0, 0, 0)

__device__ __forceinline__ void gload16(const u16* g, const short* l) {
    __builtin_amdgcn_global_load_lds(
        (__attribute__((address_space(1))) void*)g,
        (__attribute__((address_space(3))) void*)l, 16, 0, 0);
}

// ------------------------------------------------------------- x cvt + landmarks
__global__ __launch_bounds__(256) void k_cvtx(const float* __restrict__ x,
                                              u16* __restrict__ xa,
                                              float* __restrict__ part) {
    const int g = blockIdx.x;            // 0..511
    const int t = threadIdx.x;
    const float* base = x + (size_t)g * 64 * 768;
    u16* ob = xa + (size_t)g * 64 * 768;
    float s0 = 0.f, s1 = 0.f, s2 = 0.f;
    for (int r = 0; r < 64; ++r) {
        const size_t off = (size_t)r * 768;
        const float v0 = base[off + t], v1 = base[off + t + 256], v2 = base[off + t + 512];
        s0 += v0; s1 += v1; s2 += v2;
        ob[off + t] = f2bf(v0); ob[off + t + 256] = f2bf(v1); ob[off + t + 512] = f2bf(v2);
    }
    float* p = part + (size_t)g * 768;
    p[t] = s0; p[t + 256] = s1; p[t + 512] = s2;
}

__global__ void k_lmred(const float* __restrict__ part, u16* __restrict__ xa_lm) {
    const int bl = blockIdx.x;
    const int t = threadIdx.x;
    const float* p = part + (size_t)bl * 4 * 768;
    const float inv = 1.f / 256.f;
    for (int c = t; c < 768; c += 256) {
        const float s = p[c] + p[768 + c] + p[1536 + c] + p[2304 + c];
        xa_lm[(size_t)bl * 768 + c] = f2bf(s * inv);
    }
}

__global__ void k_cvtw(const float* __restrict__ qw, const float* __restrict__ kw,
                       const float* __restrict__ vw, const float* __restrict__ ow,
                       const float* __restrict__ qb, const float* __restrict__ kb,
                       const float* __restrict__ vb,
                       u16* __restrict__ wcat, u16* __restrict__ owb,
                       float* __restrict__ bcat) {
    const int yy = blockIdx.y;
    const int i = blockIdx.x * 256 + threadIdx.x;
    if (yy == 4) {
        if (i < 768)       bcat[i] = qb[i];
        else if (i < 1536) bcat[i] = kb[i - 768];
        else if (i < 2304) bcat[i] = vb[i - 1536];
        return;
    }
    const float* src = (yy == 0) ? qw : (yy == 1) ? kw : (yy == 2) ? vw : ow;
    u16* dst = (yy == 3) ? owb : wcat + (size_t)yy * 589824;
    const float4 v = ((const float4*)src)[i];
    ushort4 o;
    o.x = f2bf(v.x); o.y = f2bf(v.y); o.z = f2bf(v.z); o.w = f2bf(v.w);
    ((ushort4*)dst)[i] = o;
}

// ------------------------------------------------ GEMM: 256x256, 8-phase, BK=64
template <int MODE>
__global__ __launch_bounds__(512, 1) void k_gemm(
    const u16* __restrict__ A, const u16* __restrict__ Bw, const float* __restrict__ bias,
    u16* __restrict__ qx, u16* __restrict__ ktok, u16* __restrict__ vt,
    u16* __restrict__ klm, u16* __restrict__ vlmt, float* __restrict__ outf)
{
    __shared__ short lA[2 * 16384];
    __shared__ short lB[2 * 16384];
    const int t = threadIdx.x;
    const int wid = t >> 6, lane = t & 63, lr = lane & 15, lg = lane >> 4;
    const int wm = wid >> 2, wn = wid & 3;

    const int gx = gridDim.x;
    const int nwg = gx * gridDim.y;
    const int orig = blockIdx.x + gx * blockIdx.y;
    const int qq = nwg >> 3, rr = nwg & 7, xcd = orig & 7, ii = orig >> 3;
    const int wg = (xcd < rr ? xcd * (qq + 1) : rr * (qq + 1) + (xcd - rr) * qq) + ii;
    const int m0 = (wg / gx) * 256, n0 = (wg % gx) * 256;

    const int MMAX = (MODE == 0) ? 32895 : 32767;
    const int u0 = t, u1 = 512 + t;
    const int r0 = u0 >> 3, c0 = ((u0 & 7) ^ (r0 & 7)) * 8;
    const int r1 = u1 >> 3, c1 = ((u1 & 7) ^ (r1 & 7)) * 8;
    const u16* pA[2][2]; const u16* pB[2][2];
#pragma unroll
    for (int h = 0; h < 2; ++h) {
        int ra0 = m0 + h * 128 + r0; if (ra0 > MMAX) ra0 = MMAX;
        int ra1 = m0 + h * 128 + r1; if (ra1 > MMAX) ra1 = MMAX;
        pA[h][0] = A + (size_t)ra0 * 768 + c0;
        pA[h][1] = A + (size_t)ra1 * 768 + c1;
        pB[h][0] = Bw + (size_t)(n0 + h * 128 + r0) * 768 + c0;
        pB[h][1] = Bw + (size_t)(n0 + h * 128 + r1) * 768 + c1;
    }
    const int sa0 = ((lg) ^ (lr & 7)) * 8;
    const int sa1 = ((4 + lg) ^ (lr & 7)) * 8;

#define STG_A(S, H, T) { gload16(pA[H][0] + (T) * 64, &lA[(S)*16384 + (H)*8192 + wid*512]);      \
                         gload16(pA[H][1] + (T) * 64, &lA[(S)*16384 + (H)*8192 + 4096 + wid*512]); }
#define STG_B(S, H, T) { gload16(pB[H][0] + (T) * 64, &lB[(S)*16384 + (H)*8192 + wid*512]);      \
                         gload16(pB[H][1] + (T) * 64, &lB[(S)*16384 + (H)*8192 + 4096 + wid*512]); }

    f32x4 acc[8][4] = {};
    short8 aq[4][2], bq[4][2];

    STG_A(0, 0, 0); STG_A(0, 1, 0); STG_B(0, 0, 0); STG_B(0, 1, 0);
    STG_A(1, 0, 1); STG_A(1, 1, 1);

#pragma unroll
    for (int T = 0; T < 12; ++T) {
        const int s = T & 1;
        const short* sa = &lA[s * 16384];
        const short* sbm = &lB[s * 16384];
        if (T + 1 < 12) STG_B(s ^ 1, 0, T + 1);
        if (T < 11) asm volatile("s_waitcnt vmcnt(6)" ::: "memory");
        else        asm volatile("s_waitcnt vmcnt(0)" ::: "memory");
        __builtin_amdgcn_s_barrier();
        __builtin_amdgcn_sched_barrier(0);
#pragma unroll
        for (int mf = 0; mf < 4; ++mf) {
            const int rb = (wm * 128 + mf * 16 + lr) * 64;
            aq[mf][0] = *(const short8*)&sa[rb + sa0];
            aq[mf][1] = *(const short8*)&sa[rb + sa1];
        }
#pragma unroll
        for (int nf = 0; nf < 4; ++nf) {
            const int rb = (wn * 64 + nf * 16 + lr) * 64;
            bq[nf][0] = *(const short8*)&sbm[rb + sa0];
            bq[nf][1] = *(const short8*)&sbm[rb + sa1];
        }
        __builtin_amdgcn_s_setprio(1);
#pragma unroll
        for (int mf = 0; mf < 4; ++mf)
#pragma unroll
            for (int nf = 0; nf < 2; ++nf)
#pragma unroll
                for (int kf = 0; kf < 2; ++kf)
                    acc[mf][nf] = MFMA_BF16(aq[mf][kf], bq[nf][kf], acc[mf][nf]);
        __builtin_amdgcn_s_setprio(0);
        if (T + 1 < 12) STG_B(s ^ 1, 1, T + 1);
        __builtin_amdgcn_s_barrier();
        __builtin_amdgcn_s_setprio(1);
#pragma unroll
        for (int mf = 0; mf < 4; ++mf)
#pragma unroll
            for (int nf = 2; nf < 4; ++nf)
#pragma unroll
                for (int kf = 0; kf < 2; ++kf)
                    acc[mf][nf] = MFMA_BF16(aq[mf][kf], bq[nf][kf], acc[mf][nf]);
        __builtin_amdgcn_s_setprio(0);
        __builtin_amdgcn_s_barrier();
#pragma unroll
        for (int mf = 0; mf < 4; ++mf) {
            const int rb = (wm * 128 + (mf + 4) * 16 + lr) * 64;
            aq[mf][0] = *(const short8*)&sa[rb + sa0];
            aq[mf][1] = *(const short8*)&sa[rb + sa1];
        }
        __builtin_amdgcn_s_setprio(1);
#pragma unroll
        for (int mf = 0; mf < 4; ++mf)
#pragma unroll
            for (int nf = 0; nf < 2; ++nf)
#pragma unroll
                for (int kf = 0; kf < 2; ++kf)
                    acc[mf + 4][nf] = MFMA_BF16(aq[mf][kf], bq[nf][kf], acc[mf + 4][nf]);
        __builtin_amdgcn_s_setprio(0);
        __builtin_amdgcn_s_barrier();
        if (T + 2 < 12) { STG_A(s, 0, T + 2); STG_A(s, 1, T + 2); }
        __builtin_amdgcn_s_setprio(1);
#pragma unroll
        for (int mf = 0; mf < 4; ++mf)
#pragma unroll
            for (int nf = 2; nf < 4; ++nf)
#pragma unroll
                for (int kf = 0; kf < 2; ++kf)
                    acc[mf + 4][nf] = MFMA_BF16(aq[mf][kf], bq[nf][kf], acc[mf + 4][nf]);
        __builtin_amdgcn_s_setprio(0);
    }
#undef STG_A
#undef STG_B

    if (MODE == 0) {
        const int region = n0 / 768;             // 0=Q 1=K 2=V (uniform per block)
        if (region == 2) {
            // ---- V: packed transposed ushort4 stores direct to vt / vlmt
#pragma unroll
            for (int nf = 0; nf < 4; ++nf) {
                const int gn = n0 + wn * 64 + nf * 16 + lr;
                const float bv = bias[gn];
                const int nn = gn - 1536;
                const int h = nn >> 6, d = nn & 63;
#pragma unroll
                for (int mf = 0; mf < 8; ++mf) {
                    const int gmb = m0 + wm * 128 + mf * 16 + lg * 4;
                    ushort4 w;
                    w.x = f2bf(acc[mf][nf][0] + bv);
                    w.y = f2bf(acc[mf][nf][1] + bv);
                    w.z = f2bf(acc[mf][nf][2] + bv);
                    w.w = f2bf(acc[mf][nf][3] + bv);
                    if (gmb < 32768) {
                        const int b = gmb >> 13, ss = gmb & 8191;
                        *(ushort4*)(vt + ((size_t)(b * 12 + h) * 64 + d) * 8192 + ss) = w;
                    } else if (gmb < 32896) {
                        const int ii2 = gmb - 32768;
                        const int bb = ii2 >> 5, lmr = ii2 & 31;
                        *(ushort4*)(vlmt + ((size_t)(bb * 12 + h) * 64 + d) * 32 + lmr) = w;
                    }
                }
            }
        } else {
            // ---- Q/K: round-5 scalar stores (verbatim)
            u16* dst = (region == 0) ? qx : ktok;
#pragma unroll
            for (int nf = 0; nf < 4; ++nf) {
                const int gn = n0 + wn * 64 + nf * 16 + lr;
                const int nn = gn - region * 768;
                const int h = nn >> 6, d = nn & 63;
                const float bv = bias[gn];
#pragma unroll
                for (int mf = 0; mf < 8; ++mf) {
                    const int gmb = m0 + wm * 128 + mf * 16 + lg * 4;
#pragma unroll
                    for (int r = 0; r < 4; ++r) {
                        const int gm = gmb + r;
                        const u16 val = f2bf(acc[mf][nf][r] + bv);
                        if (gm < 32768) {
                            const int b = gm >> 13, ss = gm & 8191;
                            dst[((size_t)(b * 12 + h) * 8192 + ss) * 64 + d] = val;
                        } else if (gm < 32896 && region == 1) {
                            const int ii2 = gm - 32768;
                            klm[((size_t)((ii2 >> 5) * 12 + h) * 32 + (ii2 & 31)) * 64 + d] = val;
                        }
                    }
                }
            }
        }
    } else {
#pragma unroll
        for (int nf = 0; nf < 4; ++nf) {
            const int gn = n0 + wn * 64 + nf * 16 + lr;
            const float bvv = bias[gn];
#pragma unroll
            for (int mf = 0; mf < 8; ++mf) {
                const int gmb = m0 + wm * 128 + mf * 16 + lg * 4;
#pragma unroll
                for (int r = 0; r < 4; ++r)
                    outf[(size_t)(gmb + r) * 768 + gn] = acc[mf][nf][r] + bvv;
            }
        }
    }
}

// ---------------------------------------------------------------- attention
__global__ __launch_bounds__(256) void k_attn(
    const u16* __restrict__ q, const u16* __restrict__ ktok,
    const u16* __restrict__ klm, const u16* __restrict__ vt,
    const u16* __restrict__ vlmt, u16* __restrict__ ao)
{
    __shared__ short kls[2][32 * 72];
    __shared__ short vls[2][64 * 40];
    __shared__ short pls[4][64 * 40];
    const int t = threadIdx.x, wid = t >> 6, l = t & 63, lr = l & 15, lg = l >> 4;
    const int idx = blockIdx.x;
    const int qt = idx & 1;
    const int h  = (idx >> 1) % 12;
    const int cb = (idx >> 1) / 12;
    const int c  = cb & 15, b = cb >> 4;
    const int bh = b * 12 + h;
    const int sb = c * 512 + qt * 256 + wid * 64;

    short8 qf[4][2];
#pragma unroll
    for (int mf = 0; mf < 4; ++mf)
#pragma unroll
        for (int kf = 0; kf < 2; ++kf)
            qf[mf][kf] = *(const short8*)(q + ((size_t)bh * 8192 + sb + mf * 16 + lr) * 64
                                            + kf * 32 + lg * 8);

    f32x4 O[4][4] = {};
    float lsum[4][4] = {};

    short* pw = &pls[wid][0];
    const int kn = t >> 3, kko = (t & 7) * 8;
    const int kctx = (kn < 16) ? (kn * 2) : ((kn - 16) * 2 + 1);
    const int vd = t >> 2, vco = (t & 3) * 8;

    auto kaddr = [&](int ti) -> const u16* {
        if (ti == 0) return klm + ((size_t)bh * 32 + kctx) * 64 + kko;
        return ktok + ((size_t)bh * 8192 + c * 512 + (ti - 1) * 32 + kctx) * 64 + kko;
    };
    auto vaddr = [&](int ti) -> const u16* {
        if (ti == 0) return vlmt + ((size_t)bh * 64 + vd) * 32 + vco;
        return vt + ((size_t)bh * 64 + vd) * 8192 + c * 512 + (ti - 1) * 32 + vco;
    };

    {
        const uint4 rk0 = *(const uint4*)kaddr(0);
        const uint4 rv0 = *(const uint4*)vaddr(0);
        *(uint4*)&kls[0][kn * 72 + kko] = rk0;
        *(uint4*)&vls[0][vd * 40 + vco] = rv0;
    }
    __syncthreads();

    for (int ti = 0; ti < 17; ++ti) {
        const int cur = ti & 1, nxt = cur ^ 1;
        uint4 rk, rv;
        if (ti < 16) { rk = *(const uint4*)kaddr(ti + 1); rv = *(const uint4*)vaddr(ti + 1); }

        f32x4 sc[4][2] = {};
#pragma unroll
        for (int kf = 0; kf < 2; ++kf) {
            const short8 b0 = *(const short8*)&kls[cur][(lr)      * 72 + kf * 32 + lg * 8];
            const short8 b1 = *(const short8*)&kls[cur][(16 + lr) * 72 + kf * 32 + lg * 8];
#pragma unroll
            for (int mf = 0; mf < 4; ++mf) {
                sc[mf][0] = MFMA_BF16(qf[mf][kf], b0, sc[mf][0]);
                sc[mf][1] = MFMA_BF16(qf[mf][kf], b1, sc[mf][1]);
            }
        }

#pragma unroll
        for (int mf = 0; mf < 4; ++mf) {
#pragma unroll
            for (int r = 0; r < 4; ++r) {
                const float p0 = __expf(sc[mf][0][r] * 0.125f);
                const float p1 = __expf(sc[mf][1][r] * 0.125f);
                lsum[mf][r] += p0 + p1;
                unsigned pk;
                asm("v_cvt_pk_bf16_f32 %0, %1, %2" : "=v"(pk) : "v"(p0), "v"(p1));
                const int prow = mf * 16 + lg * 4 + r;
                ((unsigned*)pw)[prow * 20 + lr] = pk;
            }
        }

        short8 vb[4];
#pragma unroll
        for (int df = 0; df < 4; ++df)
            vb[df] = *(const short8*)&vls[cur][(df * 16 + lr) * 40 + lg * 8];
#pragma unroll
        for (int mf = 0; mf < 4; ++mf) {
            const short8 pa = *(const short8*)&pw[(mf * 16 + lr) * 40 + lg * 8];
#pragma unroll
            for (int df = 0; df < 4; ++df)
                O[mf][df] = MFMA_BF16(pa, vb[df], O[mf][df]);
        }

        if (ti < 16) {
            *(uint4*)&kls[nxt][kn * 72 + kko] = rk;
            *(uint4*)&vls[nxt][vd * 40 + vco] = rv;
        }
        __syncthreads();
    }

#pragma unroll
    for (int mf = 0; mf < 4; ++mf)
#pragma unroll
        for (int r = 0; r < 4; ++r) {
            float lv = lsum[mf][r];
            lv += __shfl_xor(lv, 1); lv += __shfl_xor(lv, 2);
            lv += __shfl_xor(lv, 4); lv += __shfl_xor(lv, 8);
            const float inv = 1.f / lv;
            const int srow = sb + mf * 16 + lg * 4 + r;
#pragma unroll
            for (int df = 0; df < 4; ++df)
                ao[((size_t)b * 8192 + srow) * 768 + h * 64 + df * 16 + lr] =
                    f2bf(O[mf][df][r] * inv);
        }
}

// ---------------------------------------------------------------- launch
extern "C" void kernel_launch(void* const* d_in, const int* in_sizes, int n_in,
                              void* d_out, int out_size, void* d_ws, size_t ws_size,
                              hipStream_t stream)
{
    const float* x  = (const float*)d_in[0];
    const float* qw = (const float*)d_in[1];
    const float* qb = (const float*)d_in[2];
    const float* kw = (const float*)d_in[3];
    const float* kb = (const float*)d_in[4];
    const float* vw = (const float*)d_in[5];
    const float* vb = (const float*)d_in[6];
    const float* ow = (const float*)d_in[7];
    const float* ob = (const float*)d_in[8];
    float* out = (float*)d_out;

    u16* xa     = (u16*)d_ws;                        // 32896 x 768 (+128 lm rows)
    u16* wcat   = xa + (size_t)32896 * 768;          // 2304 x 768
    u16* owb    = wcat + (size_t)2304 * 768;         // 768 x 768
    float* bcat = (float*)(owb + (size_t)768 * 768); // 2304
    u16* qx     = (u16*)(bcat + 2304);               // [b,h,s,d]
    u16* ktok   = qx   + (size_t)32768 * 768;        // [b,h,s,d]
    u16* vt     = ktok + (size_t)32768 * 768;        // [b,h,d,s]
    u16* klm    = vt + (size_t)32768 * 768;          // [b,h,l,d]
    u16* vlmt   = klm + 98304;                       // [b,h,d,l]
    float* part = (float*)(vlmt + 98304);            // 512 x 768
    u16* ao     = xa;                                // alias (xa dead after gemm<0>)

    k_cvtx<<<512, 256, 0, stream>>>(x, xa, part);
    k_lmred<<<128, 256, 0, stream>>>(part, xa + (size_t)32768 * 768);
    k_cvtw<<<dim3(576, 5), 256, 0, stream>>>(qw, kw, vw, ow, qb, kb, vb, wcat, owb, bcat);

    k_gemm<0><<<dim3(9, 129), 512, 0, stream>>>(xa, wcat, bcat,
                                                qx, ktok, vt, klm, vlmt, nullptr);
    k_attn<<<1536, 256, 0, stream>>>(qx, ktok, klm, vt, vlmt, ao);
    k_gemm<1><<<dim3(3, 128), 512, 0, stream>>>(ao, owb, ob,
                                                nullptr, nullptr, nullptr, nullptr, nullptr, out);
}